// Round 1
// baseline (595.534 us; speedup 1.0000x reference)
//
#include <hip/hip_runtime.h>
#include <math.h>

#define SP 32768            // 32*32*32 voxels
#define NPAD 34
#define PSP (34*34*34)      // 39304 padded voxels

// ---------------- init: zero the groupnorm accumulators ----------------
__global__ void k_init(float* acc) { acc[0] = 0.f; acc[1] = 0.f; }

// ---------------- depthwise conv3d 3x3x3 + global sum/sumsq ----------------
__global__ void k_dwconv(const float* __restrict__ x, const float* __restrict__ dw,
                         float* __restrict__ xc, float* __restrict__ acc) {
    int e = blockIdx.x * 256 + threadIdx.x;      // e over 64*32768
    int c = e >> 15, s = e & 32767;
    int d = s >> 10, h = (s >> 5) & 31, w = s & 31;
    const float* xs = x + (size_t)c * SP;
    const float* wt = dw + c * 27;
    float a = 0.f;
#pragma unroll
    for (int kd = 0; kd < 3; ++kd) {
        int zz = d + kd - 1; if ((unsigned)zz >= 32u) continue;
#pragma unroll
        for (int kh = 0; kh < 3; ++kh) {
            int yy = h + kh - 1; if ((unsigned)yy >= 32u) continue;
#pragma unroll
            for (int kw = 0; kw < 3; ++kw) {
                int xx = w + kw - 1; if ((unsigned)xx >= 32u) continue;
                a += xs[(zz << 10) + (yy << 5) + xx] * wt[kd * 9 + kh * 3 + kw];
            }
        }
    }
    xc[e] = a;
    __shared__ float rs[256], rq[256];
    rs[threadIdx.x] = a; rq[threadIdx.x] = a * a;
    __syncthreads();
    for (int off = 128; off > 0; off >>= 1) {
        if (threadIdx.x < off) {
            rs[threadIdx.x] += rs[threadIdx.x + off];
            rq[threadIdx.x] += rq[threadIdx.x + off];
        }
        __syncthreads();
    }
    if (threadIdx.x == 0) { atomicAdd(&acc[0], rs[0]); atomicAdd(&acc[1], rq[0]); }
}

// ---------------- GroupNorm(1,C) + GELU(tanh) + NCDHW->NDHWC ----------------
__global__ void k_gn_gelu(const float* __restrict__ xc, const float* __restrict__ acc,
                          const float* __restrict__ gn_w, const float* __restrict__ gn_b,
                          float* __restrict__ x1) {
    int o = blockIdx.x * 256 + threadIdx.x;      // o = s*64 + c (coalesced writes)
    int s = o >> 6, c = o & 63;
    const float Minv = 1.f / 2097152.f;
    float mu = acc[0] * Minv;
    float var = acc[1] * Minv - mu * mu;
    float rsq = rsqrtf(var + 1e-5f);
    float v = (xc[c * SP + s] - mu) * rsq * gn_w[c] + gn_b[c];
    float t = tanhf(0.7978845608028654f * (v + 0.044715f * v * v * v));
    x1[o] = 0.5f * v * (1.f + t);
}

// ---------------- input projection into padded volume [34^3, 64] ----------------
__global__ void k_inproj(const float* __restrict__ x, const float* __restrict__ inp_w,
                         const float* __restrict__ inp_b, float* __restrict__ xp) {
    int v = blockIdx.x;                          // padded voxel
    int t = threadIdx.x;                         // channel
    int dp = v / (NPAD * NPAD);
    int r = v - dp * NPAD * NPAD;
    int hp = r / NPAD, wp = r - hp * NPAD;
    if (dp == 0 || dp == 33 || hp == 0 || hp == 33 || wp == 0 || wp == 33) {
        xp[(size_t)v * 64 + t] = 0.f;
        return;                                  // whole block uniform branch
    }
    int s = ((dp - 1) << 10) + ((hp - 1) << 5) + (wp - 1);
    __shared__ float xr[64];
    xr[t] = x[t * SP + s];
    __syncthreads();
    float a = inp_b[t];
#pragma unroll 8
    for (int k = 0; k < 64; ++k) a += xr[k] * inp_w[k * 64 + t];
    xp[(size_t)v * 64 + t] = a;
}

// ---------------- offsets + mask softmax + deformable sampling + out proj ----------------
__global__ void k_main(const float* __restrict__ x1, const float* __restrict__ xp,
                       const float* __restrict__ off_w, const float* __restrict__ off_b,
                       const float* __restrict__ mask_w, const float* __restrict__ mask_b,
                       const float* __restrict__ out_w, const float* __restrict__ out_b,
                       float* __restrict__ out) {
    int s = blockIdx.x;                          // output voxel
    int t = threadIdx.x;                         // 64 lanes
    int d = s >> 10, h = (s >> 5) & 31, w = s & 31;
    __shared__ float xr[64];
    __shared__ float offs[162];
    __shared__ float msk[54];
    __shared__ float accv[64];
    xr[t] = x1[(size_t)s * 64 + t];
    __syncthreads();
    // 162 offset dots (len 64)
    for (int j = t; j < 162; j += 64) {
        float a = off_b[j];
#pragma unroll 8
        for (int k = 0; k < 64; ++k) a += xr[k] * off_w[k * 162 + j];
        offs[j] = a;
    }
    // 54 mask logits
    if (t < 54) {
        float a = mask_b[t];
#pragma unroll 8
        for (int k = 0; k < 64; ++k) a += xr[k] * mask_w[k * 54 + t];
        msk[t] = a;
    }
    __syncthreads();
    // per-group softmax over 27
    if (t < 2) {
        float mx = -1e30f;
        for (int p = 0; p < 27; ++p) mx = fmaxf(mx, msk[t * 27 + p]);
        float sm = 0.f;
        for (int p = 0; p < 27; ++p) { float e = __expf(msk[t * 27 + p] - mx); msk[t * 27 + p] = e; sm += e; }
        float inv = 1.f / sm;
        for (int p = 0; p < 27; ++p) msk[t * 27 + p] *= inv;
    }
    __syncthreads();
    int g = t >> 5, ch = t & 31;
    const float* vol = xp + g * 32 + ch;
    float acc = 0.f;
    for (int p = 0; p < 27; ++p) {
        int px = p % 3, py = (p / 3) % 3, pz = p / 9;
        float ox = offs[(g * 27 + p) * 3 + 0];
        float oy = offs[(g * 27 + p) * 3 + 1];
        float oz = offs[(g * 27 + p) * 3 + 2];
        float m = msk[g * 27 + p];
        // padded coords: ix = (w+1) + (px-1) + 0.25*ox  (axis_scale_x*cur_scale = 0.25)
        float ix = (float)(w + px) + 0.25f * ox;
        float iy = (float)(h + py) + 0.5f * oy;
        float iz = (float)(d + pz) + 0.5f * oz;
        float x0f = floorf(ix), y0f = floorf(iy), z0f = floorf(iz);
        float fx = ix - x0f, fy = iy - y0f, fz = iz - z0f;
        int x0 = (int)x0f, y0 = (int)y0f, z0 = (int)z0f;
        float sv = 0.f;
#pragma unroll
        for (int dz = 0; dz < 2; ++dz) {
            int cz = z0 + dz; if ((unsigned)cz >= 34u) continue;
            float wz = dz ? fz : 1.f - fz;
#pragma unroll
            for (int dy = 0; dy < 2; ++dy) {
                int cy = y0 + dy; if ((unsigned)cy >= 34u) continue;
                float wy = dy ? fy : 1.f - fy;
#pragma unroll
                for (int dx = 0; dx < 2; ++dx) {
                    int cx = x0 + dx; if ((unsigned)cx >= 34u) continue;
                    float wx = dx ? fx : 1.f - fx;
                    sv += wz * wy * wx * vol[(size_t)((cz * 34 + cy) * 34 + cx) * 64];
                }
            }
        }
        acc += m * sv;
    }
    accv[t] = acc;
    __syncthreads();
    float o = out_b[t];
#pragma unroll 8
    for (int k = 0; k < 64; ++k) o += accv[k] * out_w[k * 64 + t];
    out[(size_t)s * 64 + t] = o;
}

extern "C" void kernel_launch(void* const* d_in, const int* in_sizes, int n_in,
                              void* d_out, int out_size, void* d_ws, size_t ws_size,
                              hipStream_t stream) {
    const float* x      = (const float*)d_in[0];
    const float* dw_w   = (const float*)d_in[1];
    const float* gn_w   = (const float*)d_in[2];
    const float* gn_b   = (const float*)d_in[3];
    const float* inp_w  = (const float*)d_in[4];
    const float* inp_b  = (const float*)d_in[5];
    const float* off_w  = (const float*)d_in[6];
    const float* off_b  = (const float*)d_in[7];
    const float* mask_w = (const float*)d_in[8];
    const float* mask_b = (const float*)d_in[9];
    const float* out_w  = (const float*)d_in[10];
    const float* out_b  = (const float*)d_in[11];

    float* W   = (float*)d_ws;
    float* acc = W;                  // 2 floats (+pad)
    float* xc  = W + 16;             // 2,097,152
    float* x1  = xc + 2097152;       // 2,097,152
    float* xp  = x1 + 2097152;       // 39304*64 = 2,515,456
    float* out = (float*)d_out;

    k_init<<<1, 1, 0, stream>>>(acc);
    k_dwconv<<<8192, 256, 0, stream>>>(x, dw_w, xc, acc);
    k_gn_gelu<<<8192, 256, 0, stream>>>(xc, acc, gn_w, gn_b, x1);
    k_inproj<<<PSP, 64, 0, stream>>>(x, inp_w, inp_b, xp);
    k_main<<<SP, 64, 0, stream>>>(x1, xp, off_w, off_b, mask_w, mask_b,
                                  out_w, out_b, out);
}

// Round 2
// 519.815 us; speedup vs baseline: 1.1457x; 1.1457x over previous
//
#include <hip/hip_runtime.h>
#include <math.h>

#define SP 32768            // 32*32*32 voxels
#define NPAD 34
#define PSP (34*34*34)      // 39304 padded voxels

// ---------------- prep: transpose weights into lane-local row layout ----------------
// WcatT[216][64]  = concat(off_w, mask_w)^T ; bcat[216] = concat(off_b, mask_b)
// out_wT[64][64]  = out_w^T ; inp_wT[64][64] = inp_w^T
__global__ void k_prep(const float* __restrict__ off_w, const float* __restrict__ off_b,
                       const float* __restrict__ mask_w, const float* __restrict__ mask_b,
                       const float* __restrict__ out_w, const float* __restrict__ inp_w,
                       float* __restrict__ WcatT, float* __restrict__ bcat,
                       float* __restrict__ out_wT, float* __restrict__ inp_wT) {
    int j = blockIdx.x, k = threadIdx.x;
    if (j < 216) {
        WcatT[j * 64 + k] = (j < 162) ? off_w[k * 162 + j] : mask_w[k * 54 + (j - 162)];
        if (k == 0) bcat[j] = (j < 162) ? off_b[j] : mask_b[j - 162];
    } else if (j < 280) {
        int jj = j - 216;
        out_wT[jj * 64 + k] = out_w[k * 64 + jj];
    } else {
        int jj = j - 280;
        inp_wT[jj * 64 + k] = inp_w[k * 64 + jj];
    }
}

// ---------------- transpose x: NCDHW -> [s][c] ----------------
__global__ void k_transpose(const float* __restrict__ x, float* __restrict__ x_t) {
    __shared__ float tile[64][65];
    int s0 = blockIdx.x * 64;
    int row = threadIdx.x >> 6, lane = threadIdx.x & 63;
    for (int c = row; c < 64; c += 4)
        tile[c][lane] = x[(size_t)c * SP + s0 + lane];
    __syncthreads();
    for (int r = row; r < 64; r += 4)
        x_t[(size_t)(s0 + r) * 64 + lane] = tile[lane][r];
}

// ---------------- depthwise conv3d 3x3x3 + per-block sum/sumsq partials ----------------
__global__ void k_dwconv(const float* __restrict__ x, const float* __restrict__ dw,
                         float* __restrict__ xc, float* __restrict__ partials) {
    int e = blockIdx.x * 256 + threadIdx.x;      // e over 64*32768
    int c = e >> 15, s = e & 32767;
    int d = s >> 10, h = (s >> 5) & 31, w = s & 31;
    const float* xs = x + (size_t)c * SP;
    const float* wt = dw + c * 27;
    float a = 0.f;
#pragma unroll
    for (int kd = 0; kd < 3; ++kd) {
        int zz = d + kd - 1; if ((unsigned)zz >= 32u) continue;
#pragma unroll
        for (int kh = 0; kh < 3; ++kh) {
            int yy = h + kh - 1; if ((unsigned)yy >= 32u) continue;
#pragma unroll
            for (int kw = 0; kw < 3; ++kw) {
                int xx = w + kw - 1; if ((unsigned)xx >= 32u) continue;
                a += xs[(zz << 10) + (yy << 5) + xx] * wt[kd * 9 + kh * 3 + kw];
            }
        }
    }
    xc[e] = a;
    __shared__ float rs[256], rq[256];
    rs[threadIdx.x] = a; rq[threadIdx.x] = a * a;
    __syncthreads();
    for (int off = 128; off > 0; off >>= 1) {
        if (threadIdx.x < off) {
            rs[threadIdx.x] += rs[threadIdx.x + off];
            rq[threadIdx.x] += rq[threadIdx.x + off];
        }
        __syncthreads();
    }
    if (threadIdx.x == 0) {
        partials[blockIdx.x * 2 + 0] = rs[0];
        partials[blockIdx.x * 2 + 1] = rq[0];
    }
}

// ---------------- reduce 8192 partial pairs -> acc[2] ----------------
__global__ void k_reduce(const float* __restrict__ partials, float* __restrict__ acc) {
    __shared__ float rs[256], rq[256];
    float a = 0.f, b = 0.f;
    for (int i = threadIdx.x; i < 8192; i += 256) {
        a += partials[2 * i + 0];
        b += partials[2 * i + 1];
    }
    rs[threadIdx.x] = a; rq[threadIdx.x] = b;
    __syncthreads();
    for (int off = 128; off > 0; off >>= 1) {
        if (threadIdx.x < off) {
            rs[threadIdx.x] += rs[threadIdx.x + off];
            rq[threadIdx.x] += rq[threadIdx.x + off];
        }
        __syncthreads();
    }
    if (threadIdx.x == 0) { acc[0] = rs[0]; acc[1] = rq[0]; }
}

// ---------------- GroupNorm(1,C) + GELU(tanh) + NCDHW->[s][c] ----------------
__global__ void k_gn_gelu(const float* __restrict__ xc, const float* __restrict__ acc,
                          const float* __restrict__ gn_w, const float* __restrict__ gn_b,
                          float* __restrict__ x1) {
    int o = blockIdx.x * 256 + threadIdx.x;      // o = s*64 + c (coalesced writes)
    int s = o >> 6, c = o & 63;
    const float Minv = 1.f / 2097152.f;
    float mu = acc[0] * Minv;
    float var = acc[1] * Minv - mu * mu;
    float rsq = rsqrtf(var + 1e-5f);
    float v = (xc[c * SP + s] - mu) * rsq * gn_w[c] + gn_b[c];
    float t = tanhf(0.7978845608028654f * (v + 0.044715f * v * v * v));
    x1[o] = 0.5f * v * (1.f + t);
}

// ---------------- zero the padded volume ----------------
__global__ void k_zero(float4* __restrict__ p, int n4) {
    int i = blockIdx.x * blockDim.x + threadIdx.x;
    int stride = gridDim.x * blockDim.x;
    float4 z = {0.f, 0.f, 0.f, 0.f};
    for (; i < n4; i += stride) p[i] = z;
}

// ---------------- input projection into padded volume interior ----------------
__global__ void __launch_bounds__(64) k_inproj(const float* __restrict__ x_t,
                                               const float* __restrict__ inp_wT,
                                               const float* __restrict__ inp_b,
                                               float* __restrict__ xp) {
    int s = blockIdx.x, t = threadIdx.x;
    int d = s >> 10, h = (s >> 5) & 31, w = s & 31;
    __shared__ __align__(16) float xr[64];
    xr[t] = x_t[(size_t)s * 64 + t];
    __syncthreads();
    const float4* xv = (const float4*)xr;
    const float4* wv = (const float4*)(inp_wT + t * 64);
    float a = inp_b[t];
#pragma unroll
    for (int k = 0; k < 16; ++k) {
        float4 xx = xv[k], ww = wv[k];
        a += xx.x * ww.x + xx.y * ww.y + xx.z * ww.z + xx.w * ww.w;
    }
    int v = ((d + 1) * 34 + (h + 1)) * 34 + (w + 1);
    xp[(size_t)v * 64 + t] = a;
}

// ---------------- offsets + mask softmax + deformable sampling + out proj ----------------
__global__ void __launch_bounds__(64) k_main(const float* __restrict__ x1,
                                             const float* __restrict__ xp,
                                             const float* __restrict__ WcatT,
                                             const float* __restrict__ bcat,
                                             const float* __restrict__ out_wT,
                                             const float* __restrict__ out_b,
                                             float* __restrict__ out) {
    int s = blockIdx.x, t = threadIdx.x;
    int d = s >> 10, h = (s >> 5) & 31, w = s & 31;
    __shared__ __align__(16) float xr[64];
    __shared__ float om[216];
    __shared__ __align__(16) float accv[64];
    xr[t] = x1[(size_t)s * 64 + t];
    __syncthreads();
    const float4* xv = (const float4*)xr;
    // 216 fused offset+mask dots, lane-local float4 rows
#pragma unroll
    for (int i = 0; i < 4; ++i) {
        int j = t + (i << 6);
        if (j < 216) {
            const float4* wv = (const float4*)(WcatT + j * 64);
            float a = bcat[j];
#pragma unroll
            for (int k = 0; k < 16; ++k) {
                float4 xx = xv[k], ww = wv[k];
                a += xx.x * ww.x + xx.y * ww.y + xx.z * ww.z + xx.w * ww.w;
            }
            om[j] = a;
        }
    }
    __syncthreads();
    // per-group softmax over 27 (2 lanes)
    if (t < 2) {
        float mx = -1e30f;
#pragma unroll
        for (int p = 0; p < 27; ++p) mx = fmaxf(mx, om[162 + t * 27 + p]);
        float sm = 0.f;
        float e[27];
#pragma unroll
        for (int p = 0; p < 27; ++p) { e[p] = __expf(om[162 + t * 27 + p] - mx); sm += e[p]; }
        float inv = 1.f / sm;
#pragma unroll
        for (int p = 0; p < 27; ++p) om[162 + t * 27 + p] = e[p] * inv;
    }
    __syncthreads();
    int g = t >> 5;
    const float* vol = xp + (g << 5) + (t & 31);
    const float* offg = om + g * 81;
    const float* mskg = om + 162 + g * 27;
    float acc = 0.f;
#pragma unroll
    for (int p = 0; p < 27; ++p) {
        int px = p % 3, py = (p / 3) % 3, pz = p / 9;
        float ox = offg[p * 3 + 0], oy = offg[p * 3 + 1], oz = offg[p * 3 + 2];
        float m = mskg[p];
        // padded coords: ix = (w+px) + 0.25*ox (axis_scale_x*cur_scale), 0.5 for y/z
        float ix = (float)(w + px) + 0.25f * ox;
        float iy = (float)(h + py) + 0.5f * oy;
        float iz = (float)(d + pz) + 0.5f * oz;
        float xf = floorf(ix), yf = floorf(iy), zf = floorf(iz);
        float fx = ix - xf, fy = iy - yf, fz = iz - zf;
        int x0 = (int)xf, y0 = (int)yf, z0 = (int)zf;
        // branchless: validity folded into weights, coords clamped
        float wx0 = (1.f - fx) * (((unsigned)x0 < 34u) ? 1.f : 0.f);
        float wx1 = fx * (((unsigned)(x0 + 1) < 34u) ? 1.f : 0.f);
        float wy0 = (1.f - fy) * (((unsigned)y0 < 34u) ? 1.f : 0.f);
        float wy1 = fy * (((unsigned)(y0 + 1) < 34u) ? 1.f : 0.f);
        float wz0 = (1.f - fz) * (((unsigned)z0 < 34u) ? 1.f : 0.f);
        float wz1 = fz * (((unsigned)(z0 + 1) < 34u) ? 1.f : 0.f);
        int xc0 = min(max(x0, 0), 33), xc1 = min(max(x0 + 1, 0), 33);
        int yc0 = min(max(y0, 0), 33), yc1 = min(max(y0 + 1, 0), 33);
        int zc0 = min(max(z0, 0), 33), zc1 = min(max(z0 + 1, 0), 33);
        int r00 = (zc0 * 34 + yc0) * 34, r01 = (zc0 * 34 + yc1) * 34;
        int r10 = (zc1 * 34 + yc0) * 34, r11 = (zc1 * 34 + yc1) * 34;
        float v000 = vol[(size_t)(r00 + xc0) << 6], v001 = vol[(size_t)(r00 + xc1) << 6];
        float v010 = vol[(size_t)(r01 + xc0) << 6], v011 = vol[(size_t)(r01 + xc1) << 6];
        float v100 = vol[(size_t)(r10 + xc0) << 6], v101 = vol[(size_t)(r10 + xc1) << 6];
        float v110 = vol[(size_t)(r11 + xc0) << 6], v111 = vol[(size_t)(r11 + xc1) << 6];
        float sv = wz0 * (wy0 * (wx0 * v000 + wx1 * v001) + wy1 * (wx0 * v010 + wx1 * v011))
                 + wz1 * (wy0 * (wx0 * v100 + wx1 * v101) + wy1 * (wx0 * v110 + wx1 * v111));
        acc += m * sv;
    }
    accv[t] = acc;
    __syncthreads();
    const float4* av = (const float4*)accv;
    const float4* wv = (const float4*)(out_wT + t * 64);
    float o = out_b[t];
#pragma unroll
    for (int k = 0; k < 16; ++k) {
        float4 aa = av[k], ww = wv[k];
        o += aa.x * ww.x + aa.y * ww.y + aa.z * ww.z + aa.w * ww.w;
    }
    out[(size_t)s * 64 + t] = o;
}

extern "C" void kernel_launch(void* const* d_in, const int* in_sizes, int n_in,
                              void* d_out, int out_size, void* d_ws, size_t ws_size,
                              hipStream_t stream) {
    const float* x      = (const float*)d_in[0];
    const float* dw_w   = (const float*)d_in[1];
    const float* gn_w   = (const float*)d_in[2];
    const float* gn_b   = (const float*)d_in[3];
    const float* inp_w  = (const float*)d_in[4];
    const float* inp_b  = (const float*)d_in[5];
    const float* off_w  = (const float*)d_in[6];
    const float* off_b  = (const float*)d_in[7];
    const float* mask_w = (const float*)d_in[8];
    const float* mask_b = (const float*)d_in[9];
    const float* out_w  = (const float*)d_in[10];
    const float* out_b  = (const float*)d_in[11];

    float* W        = (float*)d_ws;
    float* acc      = W;                         // 2 (pad 16)
    float* partials = W + 16;                    // 16384
    float* xc       = partials + 16384;          // 2,097,152
    float* x1       = xc + 2097152;              // 2,097,152
    float* xp       = x1 + 2097152;              // 2,515,456
    float* x_t      = xp + 2515456;              // 2,097,152
    float* WcatT    = x_t + 2097152;             // 13,824
    float* bcat     = WcatT + 13824;             // 216 (pad 224)
    float* out_wT   = bcat + 224;                // 4,096
    float* inp_wT   = out_wT + 4096;             // 4,096
    float* out      = (float*)d_out;

    k_prep<<<344, 64, 0, stream>>>(off_w, off_b, mask_w, mask_b, out_w, inp_w,
                                   WcatT, bcat, out_wT, inp_wT);
    k_transpose<<<512, 256, 0, stream>>>(x, x_t);
    k_dwconv<<<8192, 256, 0, stream>>>(x, dw_w, xc, partials);
    k_reduce<<<1, 256, 0, stream>>>(partials, acc);
    k_gn_gelu<<<8192, 256, 0, stream>>>(xc, acc, gn_w, gn_b, x1);
    k_zero<<<1024, 256, 0, stream>>>((float4*)xp, 628864);
    k_inproj<<<SP, 64, 0, stream>>>(x_t, inp_wT, inp_b, xp);
    k_main<<<SP, 64, 0, stream>>>(x1, xp, WcatT, bcat, out_wT, out_b, out);
}

// Round 4
// 307.130 us; speedup vs baseline: 1.9390x; 1.6925x over previous
//
#include <hip/hip_runtime.h>
#include <math.h>

#define SP 32768            // 32*32*32 voxels
#define PW 38               // padded volume width (zero ring around 34^3 logical)
#define PW2 (PW*PW)         // 1444
#define PVOX (PW*PW*PW)     // 54872

typedef short bf16x8 __attribute__((ext_vector_type(8)));
typedef float f32x4 __attribute__((ext_vector_type(4)));

__device__ __forceinline__ unsigned short f2b(float f) {
    unsigned u = __float_as_uint(f);
    u = (u + 0x7FFFu + ((u >> 16) & 1u)) >> 16;   // RNE
    return (unsigned short)u;
}

// ---------------- prep: bf16 weight tensors in B^T (n-major) layout ----------------
__global__ void k_prep(const float* __restrict__ off_w, const float* __restrict__ mask_w,
                       const float* __restrict__ off_b, const float* __restrict__ mask_b,
                       const float* __restrict__ inp_w, const float* __restrict__ out_w,
                       unsigned short* __restrict__ WcatB, float* __restrict__ bcat,
                       unsigned short* __restrict__ inpB, unsigned short* __restrict__ outB) {
    int j = blockIdx.x, k = threadIdx.x;
    if (j < 224) {
        float v = 0.f;
        if (j < 162) v = off_w[k * 162 + j];
        else if (j < 216) v = mask_w[k * 54 + (j - 162)];
        WcatB[j * 64 + k] = f2b(v);
        if (k == 0) bcat[j] = (j < 162) ? off_b[j] : (j < 216 ? mask_b[j - 162] : 0.f);
    } else if (j < 288) {
        int n = j - 224;
        outB[n * 64 + k] = f2b(out_w[k * 64 + n]);
    } else {
        int n = j - 288;
        inpB[n * 64 + k] = f2b(inp_w[k * 64 + n]);
    }
}

// ---------------- transpose x: NCDHW -> [s][c] bf16 (coalesced both sides) ----------------
__global__ void k_transpose_b(const float* __restrict__ x, unsigned short* __restrict__ x_tb) {
    __shared__ unsigned short tile[64][66];
    int s0 = blockIdx.x * 64;
    int row = threadIdx.x >> 6, lane = threadIdx.x & 63;
    for (int c = row; c < 64; c += 4)
        tile[c][lane] = f2b(x[(size_t)c * SP + s0 + lane]);
    __syncthreads();
    for (int r = row; r < 64; r += 4)
        x_tb[(size_t)(s0 + r) * 64 + lane] = tile[lane][r];
}

// ---------------- depthwise conv3d 3x3x3 + per-block sum/sumsq partials ----------------
__global__ void k_dwconv(const float* __restrict__ x, const float* __restrict__ dw,
                         float* __restrict__ xc, float* __restrict__ partials) {
    int e = blockIdx.x * 256 + threadIdx.x;      // e over 64*32768
    int c = e >> 15, s = e & 32767;
    int d = s >> 10, h = (s >> 5) & 31, w = s & 31;
    const float* xs = x + (size_t)c * SP;
    const float* wt = dw + c * 27;
    float a = 0.f;
#pragma unroll
    for (int kd = 0; kd < 3; ++kd) {
        int zz = d + kd - 1; if ((unsigned)zz >= 32u) continue;
#pragma unroll
        for (int kh = 0; kh < 3; ++kh) {
            int yy = h + kh - 1; if ((unsigned)yy >= 32u) continue;
#pragma unroll
            for (int kw = 0; kw < 3; ++kw) {
                int xx = w + kw - 1; if ((unsigned)xx >= 32u) continue;
                a += xs[(zz << 10) + (yy << 5) + xx] * wt[kd * 9 + kh * 3 + kw];
            }
        }
    }
    xc[e] = a;
    __shared__ float rs[256], rq[256];
    rs[threadIdx.x] = a; rq[threadIdx.x] = a * a;
    __syncthreads();
    for (int off = 128; off > 0; off >>= 1) {
        if (threadIdx.x < off) {
            rs[threadIdx.x] += rs[threadIdx.x + off];
            rq[threadIdx.x] += rq[threadIdx.x + off];
        }
        __syncthreads();
    }
    if (threadIdx.x == 0) {
        partials[blockIdx.x * 2 + 0] = rs[0];
        partials[blockIdx.x * 2 + 1] = rq[0];
    }
}

// ---------------- reduce 8192 partial pairs -> acc[2] ----------------
__global__ void k_reduce(const float* __restrict__ partials, float* __restrict__ acc) {
    __shared__ float rs[256], rq[256];
    float a = 0.f, b = 0.f;
    for (int i = threadIdx.x; i < 8192; i += 256) {
        a += partials[2 * i + 0];
        b += partials[2 * i + 1];
    }
    rs[threadIdx.x] = a; rq[threadIdx.x] = b;
    __syncthreads();
    for (int off = 128; off > 0; off >>= 1) {
        if (threadIdx.x < off) {
            rs[threadIdx.x] += rs[threadIdx.x + off];
            rq[threadIdx.x] += rq[threadIdx.x + off];
        }
        __syncthreads();
    }
    if (threadIdx.x == 0) { acc[0] = rs[0]; acc[1] = rq[0]; }
}

// ---------------- GroupNorm(1,C)+GELU, tile-transposed -> x1b [s][c] bf16 ----------------
__global__ void k_gn_gelu_t(const float* __restrict__ xc, const float* __restrict__ acc,
                            const float* __restrict__ gn_w, const float* __restrict__ gn_b,
                            unsigned short* __restrict__ x1b) {
    __shared__ unsigned short tile[64][66];
    int s0 = blockIdx.x * 64;
    int row = threadIdx.x >> 6, lane = threadIdx.x & 63;
    const float Minv = 1.f / 2097152.f;
    float mu = acc[0] * Minv;
    float var = acc[1] * Minv - mu * mu;
    float rsq = rsqrtf(var + 1e-5f);
    for (int c = row; c < 64; c += 4) {
        float v = (xc[(size_t)c * SP + s0 + lane] - mu) * rsq * gn_w[c] + gn_b[c];
        float t = tanhf(0.7978845608028654f * (v + 0.044715f * v * v * v));
        tile[c][lane] = f2b(0.5f * v * (1.f + t));
    }
    __syncthreads();
    for (int r = row; r < 64; r += 4)
        x1b[(size_t)(s0 + r) * 64 + lane] = tile[lane][r];
}

// ---------------- zero the padded volume ----------------
__global__ void k_zero(float4* __restrict__ p, int n4) {
    int i = blockIdx.x * blockDim.x + threadIdx.x;
    int stride = gridDim.x * blockDim.x;
    float4 z = {0.f, 0.f, 0.f, 0.f};
    for (; i < n4; i += stride) p[i] = z;
}

// ---------------- input projection via MFMA: 16 voxels/wave -> padded volume ----------------
__global__ void __launch_bounds__(64) k_inproj(const unsigned short* __restrict__ x_tb,
                                               const unsigned short* __restrict__ inpB,
                                               const float* __restrict__ inp_b,
                                               float* __restrict__ xpad) {
    int lane = threadIdx.x, quad = lane >> 4, col = lane & 15;
    int s0 = blockIdx.x * 16;
    bf16x8 a0 = *(const bf16x8*)(x_tb + (size_t)(s0 + col) * 64 + quad * 8);
    bf16x8 a1 = *(const bf16x8*)(x_tb + (size_t)(s0 + col) * 64 + 32 + quad * 8);
    int vp[4];
#pragma unroll
    for (int r = 0; r < 4; ++r) {
        int s = s0 + (quad << 2) + r;
        // original voxel (d,h,w) lives at 38-coord (d+2,h+2,w+2)
        vp[r] = (((s >> 10) + 2) * PW + ((s >> 5) & 31) + 2) * PW + (s & 31) + 2;
    }
#pragma unroll
    for (int nt = 0; nt < 4; ++nt) {
        int n0 = nt * 16;
        bf16x8 b0 = *(const bf16x8*)(inpB + (n0 + col) * 64 + quad * 8);
        bf16x8 b1 = *(const bf16x8*)(inpB + (n0 + col) * 64 + 32 + quad * 8);
        f32x4 c = {0.f, 0.f, 0.f, 0.f};
        c = __builtin_amdgcn_mfma_f32_16x16x32_bf16(a0, b0, c, 0, 0, 0);
        c = __builtin_amdgcn_mfma_f32_16x16x32_bf16(a1, b1, c, 0, 0, 0);
        float bb = inp_b[n0 + col];
#pragma unroll
        for (int r = 0; r < 4; ++r)
            xpad[(size_t)vp[r] * 64 + n0 + col] = c[r] + bb;
    }
}

// ---------------- main: MFMA offsets/masks + softmax + sampling + MFMA out proj ----------------
__global__ void __launch_bounds__(64) k_main(const unsigned short* __restrict__ x1b,
                                             const float* __restrict__ xpad,
                                             const unsigned short* __restrict__ WcatB,
                                             const float* __restrict__ bcat,
                                             const unsigned short* __restrict__ outB,
                                             const float* __restrict__ out_b,
                                             float* __restrict__ out) {
    __shared__ float om_s[16 * 225];             // per-voxel: 162 offsets + 54 masks (+pad)
    __shared__ unsigned short smb[16 * 72];      // sampled accum, bf16, padded rows
    int lane = threadIdx.x, quad = lane >> 4, col = lane & 15;
    int s0 = blockIdx.x * 16;
    // ---- offset+mask GEMM tile: (16x64) @ (64x224) ----
    bf16x8 a0 = *(const bf16x8*)(x1b + (size_t)(s0 + col) * 64 + quad * 8);
    bf16x8 a1 = *(const bf16x8*)(x1b + (size_t)(s0 + col) * 64 + 32 + quad * 8);
#pragma unroll
    for (int jt = 0; jt < 14; ++jt) {
        int n0 = jt * 16;
        bf16x8 b0 = *(const bf16x8*)(WcatB + (n0 + col) * 64 + quad * 8);
        bf16x8 b1 = *(const bf16x8*)(WcatB + (n0 + col) * 64 + 32 + quad * 8);
        f32x4 c = {0.f, 0.f, 0.f, 0.f};
        c = __builtin_amdgcn_mfma_f32_16x16x32_bf16(a0, b0, c, 0, 0, 0);
        c = __builtin_amdgcn_mfma_f32_16x16x32_bf16(a1, b1, c, 0, 0, 0);
        float bb = bcat[n0 + col];
#pragma unroll
        for (int r = 0; r < 4; ++r)
            om_s[(quad * 4 + r) * 225 + n0 + col] = c[r] + bb;
    }
    __syncthreads();
    // ---- softmax over 27 pts, 32 rows = 16 voxels x 2 groups ----
    if (lane < 32) {
        int v = lane & 15, g = lane >> 4;
        float* m = &om_s[v * 225 + 162 + g * 27];
        float mx = m[0];
#pragma unroll
        for (int p = 1; p < 27; ++p) mx = fmaxf(mx, m[p]);
        float e[27]; float sm = 0.f;
#pragma unroll
        for (int p = 0; p < 27; ++p) { e[p] = __expf(m[p] - mx); sm += e[p]; }
        float inv = 1.f / sm;
#pragma unroll
        for (int p = 0; p < 27; ++p) m[p] = e[p] * inv;
    }
    __syncthreads();
    // ---- deformable sampling: 16 voxels, 27 points, trilinear in 38^3 zero-ring vol ----
    int g = lane >> 5;
    const char* volc = (const char*)xpad + (size_t)lane * 4;   // channel = lane
    int d = s0 >> 10, h = (s0 >> 5) & 31, w0 = s0 & 31;        // d,h uniform per block
    // 34-logical coord q maps to 38-coord q+1 (interior written at +2, orig voxel w at 34-coord w+1)
    float zb = (float)(d + 1), yb = (float)(h + 1);
    for (int v = 0; v < 16; ++v) {
        const float* orow = &om_s[v * 225 + g * 81];
        const float* mrow = &om_s[v * 225 + 162 + g * 27];
        float xb = (float)(w0 + v + 1);
        float acc = 0.f;
        int p = 0;
#pragma unroll
        for (int pz = 0; pz < 3; ++pz) {
#pragma unroll
            for (int py = 0; py < 3; ++py) {
#pragma unroll
                for (int px = 0; px < 3; ++px) {
                    float ox = orow[p * 3 + 0], oy = orow[p * 3 + 1], oz = orow[p * 3 + 2];
                    float mk = mrow[p];
                    float ix = __builtin_fmaf(0.25f, ox, xb + (float)px);
                    float iy = __builtin_fmaf(0.5f, oy, yb + (float)py);
                    float iz = __builtin_fmaf(0.5f, oz, zb + (float)pz);
                    // clamp to [0,36]: out-of-range samples land entirely in the zero
                    // ring (coords {0,1} and {34..37} are zeros) == grid_sample zeros
                    ix = fminf(fmaxf(ix, 0.f), 36.f);
                    iy = fminf(fmaxf(iy, 0.f), 36.f);
                    iz = fminf(fmaxf(iz, 0.f), 36.f);
                    float xf = floorf(ix), yf = floorf(iy), zf = floorf(iz);
                    float fx = ix - xf, fy = iy - yf, fz = iz - zf;
                    float fi = __builtin_fmaf(zf, (float)PW2, __builtin_fmaf(yf, (float)PW, xf));
                    int ib = ((int)fi) << 8;                    // byte offset, 256 B/elem row
                    const float* r00 = (const float*)(volc + ib);
                    const float* r01 = (const float*)(volc + ib + PW * 256);
                    const float* r10 = (const float*)(volc + ib + PW2 * 256);
                    const float* r11 = (const float*)(volc + ib + (PW2 + PW) * 256);
                    float v000 = r00[0], v001 = r00[64];
                    float v010 = r01[0], v011 = r01[64];
                    float v100 = r10[0], v101 = r10[64];
                    float v110 = r11[0], v111 = r11[64];
                    float wz0 = (1.f - fz) * mk, wz1 = fz * mk;
                    float w00 = wz0 * (1.f - fy), w01 = wz0 * fy;
                    float w10 = wz1 * (1.f - fy), w11 = wz1 * fy;
                    float t00 = __builtin_fmaf(fx, v001 - v000, v000);
                    float t01 = __builtin_fmaf(fx, v011 - v010, v010);
                    float t10 = __builtin_fmaf(fx, v101 - v100, v100);
                    float t11 = __builtin_fmaf(fx, v111 - v110, v110);
                    acc = __builtin_fmaf(w00, t00, acc);
                    acc = __builtin_fmaf(w01, t01, acc);
                    acc = __builtin_fmaf(w10, t10, acc);
                    acc = __builtin_fmaf(w11, t11, acc);
                    ++p;
                }
            }
        }
        smb[v * 72 + lane] = f2b(acc);
    }
    __syncthreads();
    // ---- out projection: (16x64) @ (64x64) ----
    bf16x8 oa0 = *(const bf16x8*)(smb + col * 72 + quad * 8);
    bf16x8 oa1 = *(const bf16x8*)(smb + col * 72 + 32 + quad * 8);
#pragma unroll
    for (int nt = 0; nt < 4; ++nt) {
        int n0 = nt * 16;
        bf16x8 b0 = *(const bf16x8*)(outB + (n0 + col) * 64 + quad * 8);
        bf16x8 b1 = *(const bf16x8*)(outB + (n0 + col) * 64 + 32 + quad * 8);
        f32x4 c = {0.f, 0.f, 0.f, 0.f};
        c = __builtin_amdgcn_mfma_f32_16x16x32_bf16(oa0, b0, c, 0, 0, 0);
        c = __builtin_amdgcn_mfma_f32_16x16x32_bf16(oa1, b1, c, 0, 0, 0);
        float bb = out_b[n0 + col];
#pragma unroll
        for (int r = 0; r < 4; ++r)
            out[(size_t)(s0 + quad * 4 + r) * 64 + n0 + col] = c[r] + bb;
    }
}

extern "C" void kernel_launch(void* const* d_in, const int* in_sizes, int n_in,
                              void* d_out, int out_size, void* d_ws, size_t ws_size,
                              hipStream_t stream) {
    const float* x      = (const float*)d_in[0];
    const float* dw_w   = (const float*)d_in[1];
    const float* gn_w   = (const float*)d_in[2];
    const float* gn_b   = (const float*)d_in[3];
    const float* inp_w  = (const float*)d_in[4];
    const float* inp_b  = (const float*)d_in[5];
    const float* off_w  = (const float*)d_in[6];
    const float* off_b  = (const float*)d_in[7];
    const float* mask_w = (const float*)d_in[8];
    const float* mask_b = (const float*)d_in[9];
    const float* out_w  = (const float*)d_in[10];
    const float* out_b  = (const float*)d_in[11];

    char* B = (char*)d_ws;
    float*          acc      = (float*)(B);                      // 256 B
    float*          partials = (float*)(B + 256);                // 64 KB
    float*          xc       = (float*)(B + 65792);              // 8 MB
    unsigned short* x1b      = (unsigned short*)(B + 8454400);   // 4 MB
    unsigned short* x_tb     = (unsigned short*)(B + 12648704);  // 4 MB
    float*          xpad     = (float*)(B + 16843008);           // 14.05 MB
    unsigned short* WcatB    = (unsigned short*)(B + 30890240);  // 28 KB
    float*          bcat     = (float*)(B + 30918912);           // 1 KB
    unsigned short* inpB     = (unsigned short*)(B + 30919936);  // 8 KB
    unsigned short* outB     = (unsigned short*)(B + 30928128);  // 8 KB
    float* out = (float*)d_out;

    k_prep<<<352, 64, 0, stream>>>(off_w, mask_w, off_b, mask_b, inp_w, out_w,
                                   WcatB, bcat, inpB, outB);
    k_transpose_b<<<512, 256, 0, stream>>>(x, x_tb);
    k_dwconv<<<8192, 256, 0, stream>>>(x, dw_w, xc, partials);
    k_reduce<<<1, 256, 0, stream>>>(partials, acc);
    k_gn_gelu_t<<<512, 256, 0, stream>>>(xc, acc, gn_w, gn_b, x1b);
    k_zero<<<1024, 256, 0, stream>>>((float4*)xpad, (PVOX * 64) / 4);
    k_inproj<<<2048, 64, 0, stream>>>(x_tb, inpB, inp_b, xpad);
    k_main<<<2048, 64, 0, stream>>>(x1b, xpad, WcatB, bcat, outB, out_b, out);
}

// Round 5
// 213.919 us; speedup vs baseline: 2.7839x; 1.4357x over previous
//
#include <hip/hip_runtime.h>
#include <math.h>

#define SP 32768            // 32*32*32 voxels
#define PW 38               // padded volume width (zero ring around 34^3 logical)
#define PW2 (PW*PW)         // 1444
#define PVOX (PW*PW*PW)     // 54872

typedef short bf16x8 __attribute__((ext_vector_type(8)));
typedef short s16x4 __attribute__((ext_vector_type(4)));
typedef float f32x4 __attribute__((ext_vector_type(4)));

__device__ __forceinline__ unsigned short f2b(float f) {
    unsigned u = __float_as_uint(f);
    u = (u + 0x7FFFu + ((u >> 16) & 1u)) >> 16;   // RNE
    return (unsigned short)u;
}

// ================= K1: prep (bf16 B^T weights) + x transpose + dwconv ==============
__global__ void k_front(const float* __restrict__ x, const float* __restrict__ dw,
                        const float* __restrict__ off_w, const float* __restrict__ mask_w,
                        const float* __restrict__ off_b, const float* __restrict__ mask_b,
                        const float* __restrict__ inp_w, const float* __restrict__ out_w,
                        unsigned short* __restrict__ WcatB, float* __restrict__ bcat,
                        unsigned short* __restrict__ inpB, unsigned short* __restrict__ outB,
                        unsigned short* __restrict__ x_tb,
                        float* __restrict__ xc, float* __restrict__ partials) {
    int bb = blockIdx.x, tid = threadIdx.x;
    if (bb < 88) {                               // ---- weight prep ----
        int idx = bb * 256 + tid;
        int j = idx >> 6, k = idx & 63;
        if (j < 224) {
            float v = 0.f;
            if (j < 162) v = off_w[k * 162 + j];
            else if (j < 216) v = mask_w[k * 54 + (j - 162)];
            WcatB[j * 64 + k] = f2b(v);
            if (k == 0) bcat[j] = (j < 162) ? off_b[j] : (j < 216 ? mask_b[j - 162] : 0.f);
        } else if (j < 288) {
            outB[(j - 224) * 64 + k] = f2b(out_w[k * 64 + (j - 224)]);
        } else {
            inpB[(j - 288) * 64 + k] = f2b(inp_w[k * 64 + (j - 288)]);
        }
        return;
    }
    if (bb < 600) {                              // ---- x: NCDHW -> [s][c] bf16 ----
        __shared__ unsigned short tile[64][66];
        int s0 = (bb - 88) * 64;
        int row = tid >> 6, lane = tid & 63;
        for (int c = row; c < 64; c += 4)
            tile[c][lane] = f2b(x[(size_t)c * SP + s0 + lane]);
        __syncthreads();
        for (int r = row; r < 64; r += 4)
            x_tb[(size_t)(s0 + r) * 64 + lane] = tile[lane][r];
        return;
    }
    // ---- depthwise conv 3x3x3 + per-block sum/sumsq ----
    int b3 = bb - 600;
    int e = b3 * 256 + tid;
    int c = e >> 15, s = e & 32767;
    int d = s >> 10, h = (s >> 5) & 31, w = s & 31;
    const float* xs = x + (size_t)c * SP;
    const float* wt = dw + c * 27;
    float a = 0.f;
#pragma unroll
    for (int kd = 0; kd < 3; ++kd) {
        int zz = d + kd - 1; if ((unsigned)zz >= 32u) continue;
#pragma unroll
        for (int kh = 0; kh < 3; ++kh) {
            int yy = h + kh - 1; if ((unsigned)yy >= 32u) continue;
#pragma unroll
            for (int kw = 0; kw < 3; ++kw) {
                int xx = w + kw - 1; if ((unsigned)xx >= 32u) continue;
                a += xs[(zz << 10) + (yy << 5) + xx] * wt[kd * 9 + kh * 3 + kw];
            }
        }
    }
    xc[e] = a;
    __shared__ float rs[256], rq[256];
    rs[tid] = a; rq[tid] = a * a;
    __syncthreads();
    for (int off = 128; off > 0; off >>= 1) {
        if (tid < off) { rs[tid] += rs[tid + off]; rq[tid] += rq[tid + off]; }
        __syncthreads();
    }
    if (tid == 0) {
        partials[b3 * 2 + 0] = rs[0];
        partials[b3 * 2 + 1] = rq[0];
    }
}

// ========= K2: GroupNorm(1,C)+GELU with inline partials reduce, -> x1b [s][c] bf16 =========
__global__ void k_gn(const float* __restrict__ xc, const float* __restrict__ partials,
                     const float* __restrict__ gn_w, const float* __restrict__ gn_b,
                     unsigned short* __restrict__ x1b) {
    __shared__ float rs[256], rq[256];
    __shared__ unsigned short tile[64][66];
    int tid = threadIdx.x;
    float a = 0.f, b = 0.f;
    for (int i = tid; i < 8192; i += 256) { a += partials[2 * i]; b += partials[2 * i + 1]; }
    rs[tid] = a; rq[tid] = b;
    __syncthreads();
    for (int off = 128; off > 0; off >>= 1) {
        if (tid < off) { rs[tid] += rs[tid + off]; rq[tid] += rq[tid + off]; }
        __syncthreads();
    }
    const float Minv = 1.f / 2097152.f;
    float mu = rs[0] * Minv;
    float var = rq[0] * Minv - mu * mu;
    float rsq = rsqrtf(var + 1e-5f);
    int s0 = blockIdx.x * 64;
    int row = tid >> 6, lane = tid & 63;
    for (int c = row; c < 64; c += 4) {
        float v = (xc[(size_t)c * SP + s0 + lane] - mu) * rsq * gn_w[c] + gn_b[c];
        float t = tanhf(0.7978845608028654f * (v + 0.044715f * v * v * v));
        tile[c][lane] = f2b(0.5f * v * (1.f + t));
    }
    __syncthreads();
    for (int r = row; r < 64; r += 4)
        x1b[(size_t)(s0 + r) * 64 + lane] = tile[lane][r];
}

// ========= K3: ring-zero + MFMA input projection into padded volume =========
__global__ void __launch_bounds__(64) k_vol(const unsigned short* __restrict__ x_tb,
                                            const unsigned short* __restrict__ inpB,
                                            const float* __restrict__ inp_b,
                                            float* __restrict__ xpad) {
    int t = threadIdx.x;
    if (blockIdx.x >= 2048) {                    // ---- zero the ring only ----
        int vbase = (blockIdx.x - 2048) * 16;
        for (int k = 0; k < 16; ++k) {
            int v = vbase + k;
            if (v >= PVOX) break;
            int z = v / PW2, r = v - z * PW2, y = r / PW, xq = r - y * PW;
            if (z < 2 || z > 33 || y < 2 || y > 33 || xq < 2 || xq > 33)
                xpad[(size_t)v * 64 + t] = 0.f;
        }
        return;
    }
    // ---- inproj: 16 voxels/wave ----
    int lane = t, quad = lane >> 4, col = lane & 15;
    int s0 = blockIdx.x * 16;
    bf16x8 a0 = *(const bf16x8*)(x_tb + (size_t)(s0 + col) * 64 + quad * 8);
    bf16x8 a1 = *(const bf16x8*)(x_tb + (size_t)(s0 + col) * 64 + 32 + quad * 8);
    int vp[4];
#pragma unroll
    for (int r = 0; r < 4; ++r) {
        int s = s0 + (quad << 2) + r;            // orig voxel (d,h,w) at 38-coord +2
        vp[r] = (((s >> 10) + 2) * PW + ((s >> 5) & 31) + 2) * PW + (s & 31) + 2;
    }
#pragma unroll
    for (int nt = 0; nt < 4; ++nt) {
        int n0 = nt * 16;
        bf16x8 b0 = *(const bf16x8*)(inpB + (n0 + col) * 64 + quad * 8);
        bf16x8 b1 = *(const bf16x8*)(inpB + (n0 + col) * 64 + 32 + quad * 8);
        f32x4 c = {0.f, 0.f, 0.f, 0.f};
        c = __builtin_amdgcn_mfma_f32_16x16x32_bf16(a0, b0, c, 0, 0, 0);
        c = __builtin_amdgcn_mfma_f32_16x16x32_bf16(a1, b1, c, 0, 0, 0);
        float bb = inp_b[n0 + col];
#pragma unroll
        for (int r = 0; r < 4; ++r)
            xpad[(size_t)vp[r] * 64 + n0 + col] = c[r] + bb;
    }
}

// ========= K4: main — MFMA offsets/masks + softmax + float4 sampling + MFMA out proj =========
__global__ void __launch_bounds__(64, 4) k_main(const unsigned short* __restrict__ x1b,
                                                const float* __restrict__ xpad,
                                                const unsigned short* __restrict__ WcatB,
                                                const float* __restrict__ bcat,
                                                const unsigned short* __restrict__ outB,
                                                const float* __restrict__ out_b,
                                                float* __restrict__ out) {
    __shared__ float om_s[8 * 225];              // 8 voxels: 162 offsets + 54 masks (+pad)
    __shared__ unsigned short smb[8 * 72];       // sampled accum, bf16
    int lane = threadIdx.x, quad = lane >> 4, col = lane & 15;
    // XCD swizzle: blocks sharing (blk&7) land on one XCD and cover a contiguous slab
    int sb = ((blockIdx.x & 7) << 9) + (blockIdx.x >> 3);
    int s0 = sb * 8;                             // 8 voxels per wave
    // ---- offset+mask GEMM: (8x64)@(64x224), rows 8..15 of tile duplicated ----
    int arow = s0 + (col & 7);
    bf16x8 a0 = *(const bf16x8*)(x1b + (size_t)arow * 64 + quad * 8);
    bf16x8 a1 = *(const bf16x8*)(x1b + (size_t)arow * 64 + 32 + quad * 8);
#pragma unroll
    for (int jt = 0; jt < 14; ++jt) {
        int n0 = jt * 16;
        bf16x8 b0 = *(const bf16x8*)(WcatB + (n0 + col) * 64 + quad * 8);
        bf16x8 b1 = *(const bf16x8*)(WcatB + (n0 + col) * 64 + 32 + quad * 8);
        f32x4 c = {0.f, 0.f, 0.f, 0.f};
        c = __builtin_amdgcn_mfma_f32_16x16x32_bf16(a0, b0, c, 0, 0, 0);
        c = __builtin_amdgcn_mfma_f32_16x16x32_bf16(a1, b1, c, 0, 0, 0);
        float bb = bcat[n0 + col];
        if (quad < 2) {                          // C rows 0..7 are the real voxels
#pragma unroll
            for (int r = 0; r < 4; ++r)
                om_s[(quad * 4 + r) * 225 + n0 + col] = c[r] + bb;
        }
    }
    __syncthreads();
    // ---- softmax over 27 pts: 16 rows = 8 voxels x 2 groups ----
    if (lane < 16) {
        int v = lane >> 1, g = lane & 1;
        float* m = &om_s[v * 225 + 162 + g * 27];
        float mx = m[0];
#pragma unroll
        for (int p = 1; p < 27; ++p) mx = fmaxf(mx, m[p]);
        float e[27]; float sm = 0.f;
#pragma unroll
        for (int p = 0; p < 27; ++p) { e[p] = __expf(m[p] - mx); sm += e[p]; }
        float inv = 1.f / sm;
#pragma unroll
        for (int p = 0; p < 27; ++p) m[p] = e[p] * inv;
    }
    __syncthreads();
    // ---- sampling: 2 iters x 4 voxels in parallel; lane = (voxel-quad, channel-quad) ----
    int vq = lane >> 4, cq = lane & 15, gg = cq >> 3;   // 4 channels/lane
    int d = s0 >> 10, h = (s0 >> 5) & 31, w0 = s0 & 31;
    float zb = (float)(d + 1), yb = (float)(h + 1);     // 34-logical -> 38-coord is +1
    const char* volc = (const char*)xpad + cq * 16;
#pragma unroll
    for (int i = 0; i < 2; ++i) {
        int v = (i << 2) + vq;
        const float* orow = &om_s[v * 225 + gg * 81];
        const float* mrow = &om_s[v * 225 + 162 + gg * 27];
        float xb = (float)(w0 + v + 1);
        f32x4 acc = {0.f, 0.f, 0.f, 0.f};
        int p = 0;
        for (int pz = 0; pz < 3; ++pz) {
            for (int py = 0; py < 3; ++py) {
#pragma unroll
                for (int px = 0; px < 3; ++px) {
                    float ox = orow[p * 3 + 0], oy = orow[p * 3 + 1], oz = orow[p * 3 + 2];
                    float mk = mrow[p];
                    float ix = __builtin_fmaf(0.25f, ox, xb + (float)px);
                    float iy = __builtin_fmaf(0.5f, oy, yb + (float)py);
                    float iz = __builtin_fmaf(0.5f, oz, zb + (float)pz);
                    // clamp to [0,36]: OOB samples land wholly in the zero ring
                    ix = fminf(fmaxf(ix, 0.f), 36.f);
                    iy = fminf(fmaxf(iy, 0.f), 36.f);
                    iz = fminf(fmaxf(iz, 0.f), 36.f);
                    float xf = floorf(ix), yf = floorf(iy), zf = floorf(iz);
                    float fx = ix - xf, fy = iy - yf, fz = iz - zf;
                    float fi = __builtin_fmaf(zf, (float)PW2, __builtin_fmaf(yf, (float)PW, xf));
                    int ib = ((int)fi) << 8;     // 256 B per voxel row
                    f32x4 v000 = *(const f32x4*)(volc + ib);
                    f32x4 v001 = *(const f32x4*)(volc + ib + 256);
                    f32x4 v010 = *(const f32x4*)(volc + ib + PW * 256);
                    f32x4 v011 = *(const f32x4*)(volc + ib + PW * 256 + 256);
                    f32x4 v100 = *(const f32x4*)(volc + ib + PW2 * 256);
                    f32x4 v101 = *(const f32x4*)(volc + ib + PW2 * 256 + 256);
                    f32x4 v110 = *(const f32x4*)(volc + ib + (PW2 + PW) * 256);
                    f32x4 v111 = *(const f32x4*)(volc + ib + (PW2 + PW) * 256 + 256);
                    float wz0 = (1.f - fz) * mk, wz1 = fz * mk;
                    float w00 = wz0 * (1.f - fy), w01 = wz0 * fy;
                    float w10 = wz1 * (1.f - fy), w11 = wz1 * fy;
                    f32x4 t00 = v000 + fx * (v001 - v000);
                    f32x4 t01 = v010 + fx * (v011 - v010);
                    f32x4 t10 = v100 + fx * (v101 - v100);
                    f32x4 t11 = v110 + fx * (v111 - v110);
                    acc += w00 * t00 + w01 * t01 + w10 * t10 + w11 * t11;
                    ++p;
                }
            }
        }
        s16x4 sb4;
        sb4[0] = (short)f2b(acc[0]); sb4[1] = (short)f2b(acc[1]);
        sb4[2] = (short)f2b(acc[2]); sb4[3] = (short)f2b(acc[3]);
        *(s16x4*)(smb + v * 72 + cq * 4) = sb4;
    }
    __syncthreads();
    // ---- out projection: (8x64)@(64x64), rows 8..15 duplicated ----
    int orw = col & 7;
    bf16x8 oa0 = *(const bf16x8*)(smb + orw * 72 + quad * 8);
    bf16x8 oa1 = *(const bf16x8*)(smb + orw * 72 + 32 + quad * 8);
#pragma unroll
    for (int nt = 0; nt < 4; ++nt) {
        int n0 = nt * 16;
        bf16x8 b0 = *(const bf16x8*)(outB + (n0 + col) * 64 + quad * 8);
        bf16x8 b1 = *(const bf16x8*)(outB + (n0 + col) * 64 + 32 + quad * 8);
        f32x4 c = {0.f, 0.f, 0.f, 0.f};
        c = __builtin_amdgcn_mfma_f32_16x16x32_bf16(oa0, b0, c, 0, 0, 0);
        c = __builtin_amdgcn_mfma_f32_16x16x32_bf16(oa1, b1, c, 0, 0, 0);
        float bb = out_b[n0 + col];
        if (quad < 2) {
#pragma unroll
            for (int r = 0; r < 4; ++r)
                out[(size_t)(s0 + quad * 4 + r) * 64 + n0 + col] = c[r] + bb;
        }
    }
}

extern "C" void kernel_launch(void* const* d_in, const int* in_sizes, int n_in,
                              void* d_out, int out_size, void* d_ws, size_t ws_size,
                              hipStream_t stream) {
    const float* x      = (const float*)d_in[0];
    const float* dw_w   = (const float*)d_in[1];
    const float* gn_w   = (const float*)d_in[2];
    const float* gn_b   = (const float*)d_in[3];
    const float* inp_w  = (const float*)d_in[4];
    const float* inp_b  = (const float*)d_in[5];
    const float* off_w  = (const float*)d_in[6];
    const float* off_b  = (const float*)d_in[7];
    const float* mask_w = (const float*)d_in[8];
    const float* mask_b = (const float*)d_in[9];
    const float* out_w  = (const float*)d_in[10];
    const float* out_b  = (const float*)d_in[11];

    char* B = (char*)d_ws;
    float*          partials = (float*)(B + 256);                // 64 KB
    float*          xc       = (float*)(B + 65792);              // 8 MB
    unsigned short* x1b      = (unsigned short*)(B + 8454400);   // 4 MB
    unsigned short* x_tb     = (unsigned short*)(B + 12648704);  // 4 MB
    float*          xpad     = (float*)(B + 16843008);           // 14.05 MB
    unsigned short* WcatB    = (unsigned short*)(B + 30890240);  // 28 KB
    float*          bcat     = (float*)(B + 30918912);           // 1 KB
    unsigned short* inpB     = (unsigned short*)(B + 30919936);  // 8 KB
    unsigned short* outB     = (unsigned short*)(B + 30928128);  // 8 KB
    float* out = (float*)d_out;

    k_front<<<8792, 256, 0, stream>>>(x, dw_w, off_w, mask_w, off_b, mask_b,
                                      inp_w, out_w, WcatB, bcat, inpB, outB,
                                      x_tb, xc, partials);
    k_gn<<<512, 256, 0, stream>>>(xc, partials, gn_w, gn_b, x1b);
    k_vol<<<2048 + 3430, 64, 0, stream>>>(x_tb, inpB, inp_b, xpad);
    k_main<<<4096, 64, 0, stream>>>(x1b, xpad, WcatB, bcat, outB, out_b, out);
}